// Round 5
// baseline (141.988 us; speedup 1.0000x reference)
//
#include <hip/hip_runtime.h>
#include <hip/hip_bf16.h>

#define DIMS 64
#define BATCH 8

typedef short  bf16x8 __attribute__((ext_vector_type(8)));
typedef float  f32x4v __attribute__((ext_vector_type(4)));
typedef float  f32x2v __attribute__((ext_vector_type(2)));

static __device__ __forceinline__ short f2bf(float f) {
    __hip_bfloat16 h = __float2bfloat16(f);
    return *reinterpret_cast<short*>(&h);
}

// ---------------------------------------------------------------------------
// Kernel A+R fused: blocks [0, gemmBlocks) run the MFMA GEMM role; blocks
// [gemmBlocks, ...) build row_ptr from the sorted rows and zero the sentinel
// XWh row.  (unchanged from round 4 -- passed, absmax 0.125)
// ---------------------------------------------------------------------------
__global__ __launch_bounds__(256) void gcn_pre(
    const float* __restrict__ X, const float* __restrict__ W,
    const float* __restrict__ W1, __hip_bfloat16* __restrict__ XWh,
    __hip_bfloat16* __restrict__ XW1h, const int* __restrict__ rows,
    int* __restrict__ ptr, int N, int E, int gemmBlocks)
{
    __shared__ short wlds[2 * 2 * 4 * 64 * 8];   // 8 KB: [m][kh][nt][lane][j]

    if (blockIdx.x >= gemmBlocks) {
        // ---- row_ptr role ----
        const int rb = blockIdx.x - gemmBlocks;
        if (rb == 0 && threadIdx.x < 32)
            reinterpret_cast<uint32_t*>(XWh + ((size_t)N << 6))[threadIdx.x] = 0u;
        const int e = rb * 256 + threadIdx.x;
        if (e >= E) return;
        const int r1 = rows[e];
        const int r0 = (e == 0) ? -1 : rows[e - 1];
        for (int r = r0 + 1; r <= r1; ++r) ptr[r] = e;
        if (e == E - 1) {
            for (int r = r1 + 1; r <= N; ++r) ptr[r] = E;
        }
        return;
    }

    // ---- GEMM role ----
    const int w    = threadIdx.x >> 6;      // wave 0..3
    const int lane = threadIdx.x & 63;
    const int L    = lane & 15;
    const int q    = lane >> 4;

    const int row0 = blockIdx.x * 128 + w * 16;   // tile t adds t*64

    // Build W/W1 fragment table in LDS (full coverage: 4 chunks x 256 thr).
    #pragma unroll
    for (int m = 0; m < 2; ++m) {
        const float* Wm = m ? W1 : W;
        #pragma unroll
        for (int c = 0; c < 4; ++c) {
            const int f4idx = c * 256 + threadIdx.x;          // 0..1023
            const float4 v = reinterpret_cast<const float4*>(Wm)[f4idx];
            const float vv[4] = {v.x, v.y, v.z, v.w};
            #pragma unroll
            for (int u = 0; u < 4; ++u) {
                const int i  = f4idx * 4 + u;                 // 0..4095
                const int k  = i >> 6, n = i & 63;
                const int kh = k >> 5, qq = (k >> 3) & 3, j = k & 7;
                const int nt = n >> 4, LL = n & 15;
                const int frag = ((m * 2 + kh) * 4 + nt) * 64 + qq * 16 + LL;
                wlds[frag * 8 + j] = f2bf(vv[u]);
            }
        }
    }

    // Issue all X loads for both tiles (overlaps LDS build).
    float4 xr[2][2][2];   // [tile][kh][half]
    #pragma unroll
    for (int t = 0; t < 2; ++t) {
        const int rowA = row0 + t * 64 + L;
        const int rowC = (rowA < N) ? rowA : (N - 1);   // clamped A-load row
        const float* xp = X + (size_t)rowC * 64;
        #pragma unroll
        for (int kh = 0; kh < 2; ++kh) {
            xr[t][kh][0] = reinterpret_cast<const float4*>(xp + kh * 32 + q * 8)[0];
            xr[t][kh][1] = reinterpret_cast<const float4*>(xp + kh * 32 + q * 8)[1];
        }
    }

    __syncthreads();

    // B fragments from LDS: 16 x ds_read_b128.
    bf16x8 bfrag[2][2][4];
    #pragma unroll
    for (int m = 0; m < 2; ++m)
        #pragma unroll
        for (int kh = 0; kh < 2; ++kh)
            #pragma unroll
            for (int nt = 0; nt < 4; ++nt)
                bfrag[m][kh][nt] = *reinterpret_cast<const bf16x8*>(
                    &wlds[(((m * 2 + kh) * 4 + nt) * 64 + lane) * 8]);

    #pragma unroll
    for (int t = 0; t < 2; ++t) {
        f32x4v acc[2][4];
        #pragma unroll
        for (int m = 0; m < 2; ++m)
            #pragma unroll
            for (int nt = 0; nt < 4; ++nt)
                acc[m][nt] = (f32x4v){0.f, 0.f, 0.f, 0.f};

        #pragma unroll
        for (int kh = 0; kh < 2; ++kh) {
            const float4 xa = xr[t][kh][0];
            const float4 xb = xr[t][kh][1];
            bf16x8 a;
            a[0] = f2bf(xa.x); a[1] = f2bf(xa.y); a[2] = f2bf(xa.z); a[3] = f2bf(xa.w);
            a[4] = f2bf(xb.x); a[5] = f2bf(xb.y); a[6] = f2bf(xb.z); a[7] = f2bf(xb.w);
            #pragma unroll
            for (int nt = 0; nt < 4; ++nt) {
                acc[0][nt] = __builtin_amdgcn_mfma_f32_16x16x32_bf16(
                    a, bfrag[0][kh][nt], acc[0][nt], 0, 0, 0);
                acc[1][nt] = __builtin_amdgcn_mfma_f32_16x16x32_bf16(
                    a, bfrag[1][kh][nt], acc[1][nt], 0, 0, 0);
            }
        }

        #pragma unroll
        for (int r = 0; r < 4; ++r) {
            const int row = row0 + t * 64 + q * 4 + r;
            if (row < N) {
                ushort4 p0, p1;
                p0.x = (unsigned short)f2bf(acc[0][0][r]);
                p0.y = (unsigned short)f2bf(acc[0][1][r]);
                p0.z = (unsigned short)f2bf(acc[0][2][r]);
                p0.w = (unsigned short)f2bf(acc[0][3][r]);
                p1.x = (unsigned short)f2bf(acc[1][0][r]);
                p1.y = (unsigned short)f2bf(acc[1][1][r]);
                p1.z = (unsigned short)f2bf(acc[1][2][r]);
                p1.w = (unsigned short)f2bf(acc[1][3][r]);
                *reinterpret_cast<ushort4*>(XWh  + ((size_t)row << 6) + 4 * L) = p0;
                *reinterpret_cast<ushort4*>(XW1h + ((size_t)row << 6) + 4 * L) = p1;
            }
        }
    }
}

// ---------------------------------------------------------------------------
// Kernel B: CSR row-centric aggregation. One wave = 8 rows; 8-lane group per
// row; lane d reads pi-positions [8d,8d+8) as one uint4.
// Round-5 changes:
//   - EXEC-MASKED gathers: `if (e+j < p1) raw[j] = load` -- lanes past their
//     row's end issue NO memory request (previously: branchless sentinel
//     loads, ~33% wasted TA/TD requests from batch-max quantization). The
//     p1-guard also subsumes the E-clamp (p1 <= E), removing the safe-index
//     select per j.
//   - unpack drops the 4 AND ops per uint4: a bf16 in the high half of a
//     u32 IS its f32 with garbage low-mantissa bits (<=2^-7 relative);
//     accumulate (w<<16, w) pairs directly (pk_add-friendly). Worst-case
//     added error ~0.06 abs vs 0.4875 threshold.
//   - cols index stream still software-pipelined one batch ahead.
// ---------------------------------------------------------------------------
__global__ __launch_bounds__(256) void gcn_csr(
    const __hip_bfloat16* __restrict__ XWh, const __hip_bfloat16* __restrict__ XW1h,
    const float* __restrict__ dd1, const int* __restrict__ ptr,
    const int* __restrict__ cols, float* __restrict__ out, int N, int E)
{
    const int t    = blockIdx.x * 256 + threadIdx.x;
    const int wave = t >> 6;
    const int lane = threadIdx.x & 63;
    const int g    = lane >> 3;     // group 0..7  -> row
    const int d    = lane & 7;      // pi-dim block

    const int row = wave * 8 + g;
    int p0 = 0, p1 = 0;
    float s = 0.f;
    uint4 rr = make_uint4(0u, 0u, 0u, 0u);
    if (row < N) {
        p0 = ptr[row];
        p1 = ptr[row + 1];
        s  = 1.0f / dd1[row];
        rr = *reinterpret_cast<const uint4*>(
            XW1h + (((size_t)row) << 6) + (d << 3));
    }

    f32x2v acc2[4];
    #pragma unroll
    for (int k = 0; k < 4; ++k) acc2[k] = (f32x2v){0.f, 0.f};

    // Prefetch first batch of column indices (masked; p1 <= E so in-bounds).
    int e = p0;
    uint32_t cid[BATCH];
    #pragma unroll
    for (int j = 0; j < BATCH; ++j) {
        cid[j] = 0u;
        if (e + j < p1) cid[j] = (uint32_t)cols[e + j];
    }

    while (__any(e < p1)) {
        // Issue gathers for current batch -- exec-masked, no request for
        // lanes past their row's end.
        uint4 raw[BATCH];
        #pragma unroll
        for (int j = 0; j < BATCH; ++j) {
            raw[j] = make_uint4(0u, 0u, 0u, 0u);
            if (e + j < p1)
                raw[j] = *reinterpret_cast<const uint4*>(
                    reinterpret_cast<const char*>(XWh) +
                    ((cid[j] << 7) + (uint32_t)(d << 4)));
        }
        // Prefetch next batch's indices while gathers are in flight.
        const int en = e + BATCH;
        uint32_t cnext[BATCH];
        #pragma unroll
        for (int j = 0; j < BATCH; ++j) {
            cnext[j] = 0u;
            if (en + j < p1) cnext[j] = (uint32_t)cols[en + j];
        }
        // Unpack + accumulate (no AND: high half used with garbage low bits;
        // masked-off raw[j] is exactly zero -> contributes 0.0f).
        #pragma unroll
        for (int j = 0; j < BATCH; ++j) {
            const uint32_t ww0 = raw[j].x, ww1 = raw[j].y,
                           ww2 = raw[j].z, ww3 = raw[j].w;
            f32x2v v0, v1, v2, v3;
            v0.x = __uint_as_float(ww0 << 16);
            v0.y = __uint_as_float(ww0);
            v1.x = __uint_as_float(ww1 << 16);
            v1.y = __uint_as_float(ww1);
            v2.x = __uint_as_float(ww2 << 16);
            v2.y = __uint_as_float(ww2);
            v3.x = __uint_as_float(ww3 << 16);
            v3.y = __uint_as_float(ww3);
            acc2[0] += v0;
            acc2[1] += v1;
            acc2[2] += v2;
            acc2[3] += v3;
        }
        #pragma unroll
        for (int j = 0; j < BATCH; ++j) cid[j] = cnext[j];
        e = en;
    }

    if (row < N) {
        float res[8];
        res[0] = __uint_as_float(rr.x << 16);
        res[1] = __uint_as_float(rr.x & 0xffff0000u);
        res[2] = __uint_as_float(rr.y << 16);
        res[3] = __uint_as_float(rr.y & 0xffff0000u);
        res[4] = __uint_as_float(rr.z << 16);
        res[5] = __uint_as_float(rr.z & 0xffff0000u);
        res[6] = __uint_as_float(rr.w << 16);
        res[7] = __uint_as_float(rr.w & 0xffff0000u);
        const float accs[8] = {acc2[0].x, acc2[0].y, acc2[1].x, acc2[1].y,
                               acc2[2].x, acc2[2].y, acc2[3].x, acc2[3].y};
        // natural col 2d + delta + 16t  <-  k = 4*delta + t
        #pragma unroll
        for (int tt = 0; tt < 4; ++tt) {
            f32x2v o;
            o.x = accs[tt]     * s + res[tt];        // delta=0
            o.y = accs[4 + tt] * s + res[4 + tt];    // delta=1
            __builtin_nontemporal_store(o, reinterpret_cast<f32x2v*>(
                out + ((size_t)row << 6) + tt * 16 + d * 2));
        }
    }
}

// ---------------------------------------------------------------------------
extern "C" void kernel_launch(void* const* d_in, const int* in_sizes, int n_in,
                              void* d_out, int out_size, void* d_ws, size_t ws_size,
                              hipStream_t stream) {
    const float* X   = (const float*)d_in[0];
    const float* W   = (const float*)d_in[1];
    const float* W1  = (const float*)d_in[2];
    const float* dd1 = (const float*)d_in[3];
    const int* rows  = (const int*)d_in[4];
    const int* cols  = (const int*)d_in[5];

    const int N = in_sizes[3];
    const int E = in_sizes[4];

    // ws: XWh (N+1 rows, pi-order) | XW1h (N rows, pi-order) | row_ptr (N+1)
    char* wsp = (char*)d_ws;
    __hip_bfloat16* XWh = (__hip_bfloat16*)wsp;
    size_t off = (((size_t)(N + 1) * DIMS * sizeof(__hip_bfloat16)) + 255) & ~(size_t)255;
    __hip_bfloat16* XW1h = (__hip_bfloat16*)(wsp + off);
    off += (((size_t)N * DIMS * sizeof(__hip_bfloat16)) + 255) & ~(size_t)255;
    int* row_ptr = (int*)(wsp + off);

    float* out = (float*)d_out;

    // A+R fused: GEMM role (128 rows/block) + row_ptr role in one launch
    const int gemmBlocks = (N + 127) / 128;
    const int rptrBlocks = (E + 255) / 256;
    hipLaunchKernelGGL(gcn_pre, dim3(gemmBlocks + rptrBlocks), dim3(256), 0, stream,
                       X, W, W1, XWh, XW1h, rows, row_ptr, N, E, gemmBlocks);

    // B: out[row] = (sum XWh[cols]) / dd1[row] + XW1h[row]
    const int waves  = (N + 7) / 8;
    const int blocks = (waves + 3) / 4;
    hipLaunchKernelGGL(gcn_csr, dim3(blocks), dim3(256), 0, stream,
                       XWh, XW1h, dd1, row_ptr, cols, out, N, E);
}

// Round 6
// 123.493 us; speedup vs baseline: 1.1498x; 1.1498x over previous
//
#include <hip/hip_runtime.h>
#include <hip/hip_bf16.h>

#define DIMS 64
#define BATCH 12

typedef short  bf16x8 __attribute__((ext_vector_type(8)));
typedef float  f32x4v __attribute__((ext_vector_type(4)));
typedef float  f32x2v __attribute__((ext_vector_type(2)));

static __device__ __forceinline__ short f2bf(float f) {
    __hip_bfloat16 h = __float2bfloat16(f);
    return *reinterpret_cast<short*>(&h);
}

// ---------------------------------------------------------------------------
// Kernel A+R fused: blocks [0, gemmBlocks) run the MFMA GEMM role; blocks
// [gemmBlocks, ...) build row_ptr from the sorted rows and zero the sentinel
// XWh row.  (unchanged -- passed r4/r5, absmax 0.125, ~6-8 us)
// ---------------------------------------------------------------------------
__global__ __launch_bounds__(256) void gcn_pre(
    const float* __restrict__ X, const float* __restrict__ W,
    const float* __restrict__ W1, __hip_bfloat16* __restrict__ XWh,
    __hip_bfloat16* __restrict__ XW1h, const int* __restrict__ rows,
    int* __restrict__ ptr, int N, int E, int gemmBlocks)
{
    __shared__ short wlds[2 * 2 * 4 * 64 * 8];   // 8 KB: [m][kh][nt][lane][j]

    if (blockIdx.x >= gemmBlocks) {
        // ---- row_ptr role ----
        const int rb = blockIdx.x - gemmBlocks;
        if (rb == 0 && threadIdx.x < 32)
            reinterpret_cast<uint32_t*>(XWh + ((size_t)N << 6))[threadIdx.x] = 0u;
        const int e = rb * 256 + threadIdx.x;
        if (e >= E) return;
        const int r1 = rows[e];
        const int r0 = (e == 0) ? -1 : rows[e - 1];
        for (int r = r0 + 1; r <= r1; ++r) ptr[r] = e;
        if (e == E - 1) {
            for (int r = r1 + 1; r <= N; ++r) ptr[r] = E;
        }
        return;
    }

    // ---- GEMM role ----
    const int w    = threadIdx.x >> 6;      // wave 0..3
    const int lane = threadIdx.x & 63;
    const int L    = lane & 15;
    const int q    = lane >> 4;

    const int row0 = blockIdx.x * 128 + w * 16;   // tile t adds t*64

    // Build W/W1 fragment table in LDS (full coverage: 4 chunks x 256 thr).
    #pragma unroll
    for (int m = 0; m < 2; ++m) {
        const float* Wm = m ? W1 : W;
        #pragma unroll
        for (int c = 0; c < 4; ++c) {
            const int f4idx = c * 256 + threadIdx.x;          // 0..1023
            const float4 v = reinterpret_cast<const float4*>(Wm)[f4idx];
            const float vv[4] = {v.x, v.y, v.z, v.w};
            #pragma unroll
            for (int u = 0; u < 4; ++u) {
                const int i  = f4idx * 4 + u;                 // 0..4095
                const int k  = i >> 6, n = i & 63;
                const int kh = k >> 5, qq = (k >> 3) & 3, j = k & 7;
                const int nt = n >> 4, LL = n & 15;
                const int frag = ((m * 2 + kh) * 4 + nt) * 64 + qq * 16 + LL;
                wlds[frag * 8 + j] = f2bf(vv[u]);
            }
        }
    }

    // Issue all X loads for both tiles (overlaps LDS build).
    float4 xr[2][2][2];   // [tile][kh][half]
    #pragma unroll
    for (int t = 0; t < 2; ++t) {
        const int rowA = row0 + t * 64 + L;
        const int rowC = (rowA < N) ? rowA : (N - 1);   // clamped A-load row
        const float* xp = X + (size_t)rowC * 64;
        #pragma unroll
        for (int kh = 0; kh < 2; ++kh) {
            xr[t][kh][0] = reinterpret_cast<const float4*>(xp + kh * 32 + q * 8)[0];
            xr[t][kh][1] = reinterpret_cast<const float4*>(xp + kh * 32 + q * 8)[1];
        }
    }

    __syncthreads();

    // B fragments from LDS: 16 x ds_read_b128.
    bf16x8 bfrag[2][2][4];
    #pragma unroll
    for (int m = 0; m < 2; ++m)
        #pragma unroll
        for (int kh = 0; kh < 2; ++kh)
            #pragma unroll
            for (int nt = 0; nt < 4; ++nt)
                bfrag[m][kh][nt] = *reinterpret_cast<const bf16x8*>(
                    &wlds[(((m * 2 + kh) * 4 + nt) * 64 + lane) * 8]);

    #pragma unroll
    for (int t = 0; t < 2; ++t) {
        f32x4v acc[2][4];
        #pragma unroll
        for (int m = 0; m < 2; ++m)
            #pragma unroll
            for (int nt = 0; nt < 4; ++nt)
                acc[m][nt] = (f32x4v){0.f, 0.f, 0.f, 0.f};

        #pragma unroll
        for (int kh = 0; kh < 2; ++kh) {
            const float4 xa = xr[t][kh][0];
            const float4 xb = xr[t][kh][1];
            bf16x8 a;
            a[0] = f2bf(xa.x); a[1] = f2bf(xa.y); a[2] = f2bf(xa.z); a[3] = f2bf(xa.w);
            a[4] = f2bf(xb.x); a[5] = f2bf(xb.y); a[6] = f2bf(xb.z); a[7] = f2bf(xb.w);
            #pragma unroll
            for (int nt = 0; nt < 4; ++nt) {
                acc[0][nt] = __builtin_amdgcn_mfma_f32_16x16x32_bf16(
                    a, bfrag[0][kh][nt], acc[0][nt], 0, 0, 0);
                acc[1][nt] = __builtin_amdgcn_mfma_f32_16x16x32_bf16(
                    a, bfrag[1][kh][nt], acc[1][nt], 0, 0, 0);
            }
        }

        #pragma unroll
        for (int r = 0; r < 4; ++r) {
            const int row = row0 + t * 64 + q * 4 + r;
            if (row < N) {
                ushort4 p0, p1;
                p0.x = (unsigned short)f2bf(acc[0][0][r]);
                p0.y = (unsigned short)f2bf(acc[0][1][r]);
                p0.z = (unsigned short)f2bf(acc[0][2][r]);
                p0.w = (unsigned short)f2bf(acc[0][3][r]);
                p1.x = (unsigned short)f2bf(acc[1][0][r]);
                p1.y = (unsigned short)f2bf(acc[1][1][r]);
                p1.z = (unsigned short)f2bf(acc[1][2][r]);
                p1.w = (unsigned short)f2bf(acc[1][3][r]);
                *reinterpret_cast<ushort4*>(XWh  + ((size_t)row << 6) + 4 * L) = p0;
                *reinterpret_cast<ushort4*>(XW1h + ((size_t)row << 6) + 4 * L) = p1;
            }
        }
    }
}

// ---------------------------------------------------------------------------
// Kernel B: CSR row-centric aggregation. One wave = 8 rows; 8-lane group per
// row; lane d reads pi-positions [8d,8d+8) as one uint4.
// Round-6: REVERT r5's exec-masked gathers (divergent CF around loads forced
// conservative waitcnt at joins -> +50% on this latency-bound kernel; r5
// counters: VALUBusy 27%, HBM 28%, nothing busy). Back to r4's straight-line
// branchless sentinel gathers (compiler emits counted vmcnt). Kept from r5:
// AND-free unpack (absmax stayed 0.125). New: BATCH 12 -- wave-max degree
// ~24 = 2 full batches (no quantization waste), raw[]=48 VGPR -> ~68 total,
// ~7 waves/SIMD, in-flight misses/SIMD ~64 -> ~84.
// ---------------------------------------------------------------------------
__global__ __launch_bounds__(256) void gcn_csr(
    const __hip_bfloat16* __restrict__ XWh, const __hip_bfloat16* __restrict__ XW1h,
    const float* __restrict__ dd1, const int* __restrict__ ptr,
    const int* __restrict__ cols, float* __restrict__ out, int N, int E)
{
    const int t    = blockIdx.x * 256 + threadIdx.x;
    const int wave = t >> 6;
    const int lane = threadIdx.x & 63;
    const int g    = lane >> 3;     // group 0..7  -> row
    const int d    = lane & 7;      // pi-dim block

    const int row = wave * 8 + g;
    int p0 = 0, p1 = 0;
    float s = 0.f;
    uint4 rr = make_uint4(0u, 0u, 0u, 0u);
    if (row < N) {
        p0 = ptr[row];
        p1 = ptr[row + 1];
        s  = 1.0f / dd1[row];
        rr = *reinterpret_cast<const uint4*>(
            XW1h + (((size_t)row) << 6) + (d << 3));
    }

    f32x2v acc2[4];
    #pragma unroll
    for (int k = 0; k < 4; ++k) acc2[k] = (f32x2v){0.f, 0.f};

    // Prefetch first batch of column indices (sentinel-mapped, branchless).
    int e = p0;
    int cidx[BATCH];
    #pragma unroll
    for (int j = 0; j < BATCH; ++j) {
        const int ee = e + j;
        const int es = (ee < E) ? ee : (E - 1);   // safe index read
        const int cl = cols[es];
        cidx[j] = (ee < p1) ? cl : N;             // sentinel -> zero row
    }

    while (__any(e < p1)) {
        // Issue gathers for current batch (straight-line, unconditional).
        uint4 raw[BATCH];
        #pragma unroll
        for (int j = 0; j < BATCH; ++j) {
            const uint32_t off = ((uint32_t)cidx[j] << 7) + (uint32_t)(d << 4);
            raw[j] = *reinterpret_cast<const uint4*>(
                reinterpret_cast<const char*>(XWh) + off);
        }
        // Prefetch next batch's indices while gathers are in flight.
        const int en = e + BATCH;
        int cnext[BATCH];
        #pragma unroll
        for (int j = 0; j < BATCH; ++j) {
            const int ee = en + j;
            const int es = (ee < E) ? ee : (E - 1);
            const int cl = cols[es];
            cnext[j] = (ee < p1) ? cl : N;
        }
        // Unpack + accumulate. AND-free: bf16 in high half of u32 IS its f32
        // with garbage low-mantissa bits (<=2^-7 rel); sentinel rows are
        // exact zeros so waste slots contribute +0.0f.
        #pragma unroll
        for (int j = 0; j < BATCH; ++j) {
            const uint32_t ww0 = raw[j].x, ww1 = raw[j].y,
                           ww2 = raw[j].z, ww3 = raw[j].w;
            f32x2v v0, v1, v2, v3;
            v0.x = __uint_as_float(ww0 << 16);
            v0.y = __uint_as_float(ww0);
            v1.x = __uint_as_float(ww1 << 16);
            v1.y = __uint_as_float(ww1);
            v2.x = __uint_as_float(ww2 << 16);
            v2.y = __uint_as_float(ww2);
            v3.x = __uint_as_float(ww3 << 16);
            v3.y = __uint_as_float(ww3);
            acc2[0] += v0;
            acc2[1] += v1;
            acc2[2] += v2;
            acc2[3] += v3;
        }
        #pragma unroll
        for (int j = 0; j < BATCH; ++j) cidx[j] = cnext[j];
        e = en;
    }

    if (row < N) {
        float res[8];
        res[0] = __uint_as_float(rr.x << 16);
        res[1] = __uint_as_float(rr.x & 0xffff0000u);
        res[2] = __uint_as_float(rr.y << 16);
        res[3] = __uint_as_float(rr.y & 0xffff0000u);
        res[4] = __uint_as_float(rr.z << 16);
        res[5] = __uint_as_float(rr.z & 0xffff0000u);
        res[6] = __uint_as_float(rr.w << 16);
        res[7] = __uint_as_float(rr.w & 0xffff0000u);
        const float accs[8] = {acc2[0].x, acc2[0].y, acc2[1].x, acc2[1].y,
                               acc2[2].x, acc2[2].y, acc2[3].x, acc2[3].y};
        // natural col 2d + delta + 16t  <-  k = 4*delta + t
        #pragma unroll
        for (int tt = 0; tt < 4; ++tt) {
            f32x2v o;
            o.x = accs[tt]     * s + res[tt];        // delta=0
            o.y = accs[4 + tt] * s + res[4 + tt];    // delta=1
            __builtin_nontemporal_store(o, reinterpret_cast<f32x2v*>(
                out + ((size_t)row << 6) + tt * 16 + d * 2));
        }
    }
}

// ---------------------------------------------------------------------------
extern "C" void kernel_launch(void* const* d_in, const int* in_sizes, int n_in,
                              void* d_out, int out_size, void* d_ws, size_t ws_size,
                              hipStream_t stream) {
    const float* X   = (const float*)d_in[0];
    const float* W   = (const float*)d_in[1];
    const float* W1  = (const float*)d_in[2];
    const float* dd1 = (const float*)d_in[3];
    const int* rows  = (const int*)d_in[4];
    const int* cols  = (const int*)d_in[5];

    const int N = in_sizes[3];
    const int E = in_sizes[4];

    // ws: XWh (N+1 rows, pi-order) | XW1h (N rows, pi-order) | row_ptr (N+1)
    char* wsp = (char*)d_ws;
    __hip_bfloat16* XWh = (__hip_bfloat16*)wsp;
    size_t off = (((size_t)(N + 1) * DIMS * sizeof(__hip_bfloat16)) + 255) & ~(size_t)255;
    __hip_bfloat16* XW1h = (__hip_bfloat16*)(wsp + off);
    off += (((size_t)N * DIMS * sizeof(__hip_bfloat16)) + 255) & ~(size_t)255;
    int* row_ptr = (int*)(wsp + off);

    float* out = (float*)d_out;

    // A+R fused: GEMM role (128 rows/block) + row_ptr role in one launch
    const int gemmBlocks = (N + 127) / 128;
    const int rptrBlocks = (E + 255) / 256;
    hipLaunchKernelGGL(gcn_pre, dim3(gemmBlocks + rptrBlocks), dim3(256), 0, stream,
                       X, W, W1, XWh, XW1h, rows, row_ptr, N, E, gemmBlocks);

    // B: out[row] = (sum XWh[cols]) / dd1[row] + XW1h[row]
    const int waves  = (N + 7) / 8;
    const int blocks = (waves + 3) / 4;
    hipLaunchKernelGGL(gcn_csr, dim3(blocks), dim3(256), 0, stream,
                       XWh, XW1h, dd1, row_ptr, cols, out, N, E);
}